// Round 2
// baseline (493.126 us; speedup 1.0000x reference)
//
#include <hip/hip_runtime.h>
#include <cstdint>
#include <cstddef>

// R4 strategy:
//  1) absmax(x) & absmax(W) in ONE dispatch: grid-stride per-block partials
//     (no atomics), then a 2-block final-reduce -> sat[0]=sat_x, sat[1]=sat_w,
//     and PRECOMPUTED reciprocals sat[2]=127/clamp(sat_x), sat[3]=127/clamp(sat_w)
//     so the quant pass does zero divides.
//  2) fused quantize: x -> int8 [M,K], W -> int8 [N,K]. 64B per thread
//     (16 floats -> one int4 of 16 int8), multiply-by-reciprocal + rintf +
//     clamp [-128,127]. Memory-bound (~26 VALU / 64B) instead of the previous
//     VALU-bound 4-precise-divides-per-16B version.
//  3) int8 MFMA GEMM unchanged from R3 (verified: 219us, MfmaUtil 26%,
//     LDS bank conflicts == 0): 128x128 tile, BK=128 bytes, global_load_lds
//     width 16, mfma_i32_16x16x64_i8, chunk-XOR LDS swizzle, XCD block swizzle.

typedef int v4i __attribute__((ext_vector_type(4)));

__device__ __forceinline__ void async_copy16(const void* g, void* s) {
  __builtin_amdgcn_global_load_lds(
      (const __attribute__((address_space(1))) void*)g,
      (__attribute__((address_space(3))) void*)s, 16, 0, 0);
}

__device__ __forceinline__ float block_max(float m) {
  __shared__ float smax[4];
#pragma unroll
  for (int off = 32; off > 0; off >>= 1)
    m = fmaxf(m, __shfl_down(m, off, 64));
  if ((threadIdx.x & 63) == 0) smax[threadIdx.x >> 6] = m;
  __syncthreads();
  return fmaxf(fmaxf(smax[0], smax[1]), fmaxf(smax[2], smax[3]));
}

#define NBX 1024  // partial blocks for x
#define NBW 512   // partial blocks for W

__global__ __launch_bounds__(256) void absmax_partial_kernel(
    const float4* __restrict__ x, int xn4, const float4* __restrict__ w,
    int wn4, float* __restrict__ px, float* __restrict__ pw) {
  const float4* src;
  float* dst;
  int n4, bid, nb;
  if (blockIdx.x < NBX) {
    src = x; n4 = xn4; dst = px; bid = blockIdx.x; nb = NBX;
  } else {
    src = w; n4 = wn4; dst = pw; bid = blockIdx.x - NBX; nb = NBW;
  }
  float m = 0.0f;
  for (int i = bid * 256 + threadIdx.x; i < n4; i += nb * 256) {
    float4 v = src[i];
    m = fmaxf(m, fmaxf(fmaxf(fabsf(v.x), fabsf(v.y)),
                       fmaxf(fabsf(v.z), fabsf(v.w))));
  }
  m = block_max(m);
  if (threadIdx.x == 0) dst[bid] = m;
}

__global__ __launch_bounds__(256) void absmax_final_kernel(
    const float* __restrict__ px, const float* __restrict__ pw,
    float* __restrict__ sat) {
  const float* src = (blockIdx.x == 0) ? px : pw;
  const int n = (blockIdx.x == 0) ? NBX : NBW;
  float m = 0.0f;
  for (int i = threadIdx.x; i < n; i += 256) m = fmaxf(m, src[i]);
  m = block_max(m);
  if (threadIdx.x == 0) {
    sat[blockIdx.x] = m;
    // reciprocal of scale, computed ONCE (precise divide) so the quant pass
    // is pure multiply. scale = max(m,1e-8)/127 ; inv = 127/max(m,1e-8).
    sat[2 + blockIdx.x] = 127.0f / fmaxf(m, 1e-8f);
  }
}

__device__ __forceinline__ int pack4(float4 v, float inv) {
  int a = (int)fminf(fmaxf(rintf(v.x * inv), -128.0f), 127.0f);
  int b = (int)fminf(fmaxf(rintf(v.y * inv), -128.0f), 127.0f);
  int c = (int)fminf(fmaxf(rintf(v.z * inv), -128.0f), 127.0f);
  int d = (int)fminf(fmaxf(rintf(v.w * inv), -128.0f), 127.0f);
  return (a & 255) | ((b & 255) << 8) | ((c & 255) << 16) | ((d & 255) << 24);
}

#define QNB 2048  // quant grid blocks

__global__ __launch_bounds__(256) void quant_fused_kernel(
    const float4* __restrict__ x, int xn16, const float4* __restrict__ w,
    int wn16, const float* __restrict__ sat, int4* __restrict__ xq,
    int4* __restrict__ wq) {
  const float invx = sat[2];
  const float invw = sat[3];
  const int nth = QNB * 256;
  const int t = blockIdx.x * 256 + threadIdx.x;
  // x: one unit = 4 consecutive float4 (64B) -> one int4 (16 int8)
  for (int u = t; u < xn16; u += nth) {
    const float4* p = x + (size_t)u * 4;
    int4 o;
    o.x = pack4(p[0], invx);
    o.y = pack4(p[1], invx);
    o.z = pack4(p[2], invx);
    o.w = pack4(p[3], invx);
    xq[u] = o;
  }
  for (int u = t; u < wn16; u += nth) {
    const float4* p = w + (size_t)u * 4;
    int4 o;
    o.x = pack4(p[0], invw);
    o.y = pack4(p[1], invw);
    o.z = pack4(p[2], invw);
    o.w = pack4(p[3], invw);
    wq[u] = o;
  }
}

// C[m,n] = sum_k A[m,k]*B[n,k]  (A = x_int8 [M,K], B = w_int8 [N,K]).
// 128x128 tile, BK = 128 int8 elements (128 bytes per row).
__global__ __launch_bounds__(256) void i8_gemm_kernel(
    const signed char* __restrict__ Aq, const signed char* __restrict__ Bq,
    const float* __restrict__ bias, const float* __restrict__ sat,
    float* __restrict__ out, int M, int N, int K) {
  __shared__ signed char Als[128 * 128];
  __shared__ signed char Bls[128 * 128];

  const int tid = threadIdx.x;
  const int lane = tid & 63;
  const int wave = tid >> 6;
  const int wm = (wave & 1) * 64;
  const int wn = (wave >> 1) * 64;

  // XCD-aware block swizzle (bijective since nwg % 8 == 0 for this shape).
  const int nwg = gridDim.x * gridDim.y;
  int bid = blockIdx.y * gridDim.x + blockIdx.x;
  if ((nwg & 7) == 0) bid = (bid & 7) * (nwg >> 3) + (bid >> 3);
  const int N0 = (bid % gridDim.x) * 128;
  const int M0 = (bid / gridDim.x) * 128;

  // ---- staging (write side) ----
  // Thread t stages rows (srow + 32*r), r=0..3, chunk slot sb (8x16B chunks
  // per 128B row). LDS slot is FORCED to wave_base + lane*16 by
  // global_load_lds; slot (row, sb) holds global chunk cg = sb ^ (row&7).
  // row&7 == srow&7 (row+32r keeps low 3 bits), so cg is loop-invariant.
  const int srow = tid >> 3;  // 0..31
  const int sb = tid & 7;     // LDS chunk slot 0..7
  const int cg = sb ^ (srow & 7);
  const signed char* Ag = Aq + (size_t)(M0 + srow) * K + cg * 16;
  const signed char* Bg = Bq + (size_t)(N0 + srow) * K + cg * 16;
  signed char* AlsP = &Als[srow * 128 + sb * 16];
  signed char* BlsP = &Bls[srow * 128 + sb * 16];

  // ---- read side ----
  // A-fragment for mfma_i32_16x16x64_i8: lane holds row (wm+t*16+r15),
  // k-bytes chunk c = ks*4 + (lane>>4) (ks = 64-elem K-slice 0/1).
  // That chunk sits at slot c ^ (row&7); row&7 == r15&7.
  const int r15 = lane & 15;
  const int rx = r15 & 7;
  const int q4 = lane >> 4;
  const int kb0 = ((q4) ^ rx) * 16;      // ks=0 de-swizzled byte offset
  const int kb1 = ((4 + q4) ^ rx) * 16;  // ks=1

  v4i acc[4][4] = {};

  for (int kt = 0; kt < K; kt += 128) {
    __syncthreads();
#pragma unroll
    for (int r = 0; r < 4; ++r) {
      async_copy16(Ag + kt + (size_t)(32 * r) * K, AlsP + 32 * r * 128);
      async_copy16(Bg + kt + (size_t)(32 * r) * K, BlsP + 32 * r * 128);
    }
    __syncthreads();

#pragma unroll
    for (int ks = 0; ks < 2; ++ks) {
      const int kb = ks ? kb1 : kb0;
      v4i af[4], bf[4];
#pragma unroll
      for (int t = 0; t < 4; ++t) {
        af[t] = *(const v4i*)&Als[(wm + t * 16 + r15) * 128 + kb];
        bf[t] = *(const v4i*)&Bls[(wn + t * 16 + r15) * 128 + kb];
      }
#pragma unroll
      for (int tm = 0; tm < 4; ++tm)
#pragma unroll
        for (int tn = 0; tn < 4; ++tn)
          acc[tm][tn] = __builtin_amdgcn_mfma_i32_16x16x64_i8(
              af[tm], bf[tn], acc[tm][tn], 0, 0, 0);
    }
  }

  const float act_s = fmaxf(sat[0], 1e-8f) / 127.0f;
  const float w_s = fmaxf(sat[1], 1e-8f) / 127.0f;
  const float bscale = act_s * w_s;

  // C/D layout (16x16 shapes): col = lane&15, row = (lane>>4)*4 + reg
#pragma unroll
  for (int tn = 0; tn < 4; ++tn) {
    const int col = N0 + wn + tn * 16 + r15;
    const float fb = rintf(bias[col] / bscale);
#pragma unroll
    for (int tm = 0; tm < 4; ++tm) {
      const int row0 = M0 + wm + tm * 16 + q4 * 4;
#pragma unroll
      for (int r = 0; r < 4; ++r) {
        out[(size_t)(row0 + r) * N + col] =
            ((float)acc[tm][tn][r] + fb) * bscale;
      }
    }
  }
}

extern "C" void kernel_launch(void* const* d_in, const int* in_sizes, int n_in,
                              void* d_out, int out_size, void* d_ws,
                              size_t ws_size, hipStream_t stream) {
  const float* x = (const float*)d_in[0];
  const float* W = (const float*)d_in[1];
  const float* b = (const float*)d_in[2];
  float* out = (float*)d_out;

  const int Dout = in_sizes[2];      // 4096
  const int K = in_sizes[1] / Dout;  // 4096
  const int M = in_sizes[0] / K;     // 8192
  const int N = Dout;

  // ws layout: sat[2]+inv[2] | px[NBX] | pw[NBW] | (8KB align) xq[M*K] | wq[N*K]
  float* sat = (float*)d_ws;
  float* px = sat + 16;
  float* pw = px + NBX;
  signed char* xq = (signed char*)d_ws + 8192;
  signed char* wq = xq + (size_t)M * K;

  const int xn4 = in_sizes[0] / 4;
  const int wn4 = in_sizes[1] / 4;

  absmax_partial_kernel<<<NBX + NBW, 256, 0, stream>>>(
      (const float4*)x, xn4, (const float4*)W, wn4, px, pw);
  absmax_final_kernel<<<2, 256, 0, stream>>>(px, pw, sat);
  quant_fused_kernel<<<QNB, 256, 0, stream>>>(
      (const float4*)x, xn4 / 4, (const float4*)W, wn4 / 4, sat, (int4*)xq,
      (int4*)wq);

  dim3 grid(N / 128, M / 128);
  i8_gemm_kernel<<<grid, 256, 0, stream>>>(xq, wq, b, sat, out, M, N, K);
}

// Round 4
// 438.249 us; speedup vs baseline: 1.1252x; 1.1252x over previous
//
#include <hip/hip_runtime.h>
#include <cstdint>
#include <cstddef>

// R5 strategy (resubmit — previous round was an infra failure, not a kernel
// signal; sync structure re-audited: uniform barriers, balanced vmcnt ledger,
// barrier-guaranteed WAR/RAW on the 4-deep circular buffer):
//  1) absmax partials (no atomics) -> 2-block final reduce -> sat[0..1] + precomputed
//     reciprocals sat[2..3].
//  2) fused quantize x->int8 [M,K], W->int8 [N,K] (64B/thread, mul-by-reciprocal).
//  3) int8 MFMA GEMM, 256x256 tile, 8 waves (2Mx4N), BK=64 bytes, 4-deep
//     circular LDS K-tile pipeline (4 x 32KiB = 128KiB):
//       - stage tile t+3 while computing tile t; target slot was freed by a
//         BARRIER one tile ago -> write-after-read safety is barrier-guaranteed.
//       - counted s_waitcnt vmcnt(8) once per K-tile (2 tiles in flight),
//         never 0 in the main loop (T4); tail drains 8->4->0.
//       - 2 phases per K-tile (m-half split): 16 MFMA/phase, B-frags reused
//         across phases, s_setprio(1) around MFMA cluster (T5).
//       - LDS chunk swizzle slot=(chunk+(row>>1))&3: every 8-lane group of a
//         ds_read_b128 covers all 32 banks (conflict-free); global source is
//         pre-swizzled with the inverse permutation since global_load_lds
//         forces a linear LDS dest (= tid*16).
//       - XCD-aware block swizzle (nwg = 512, %8==0 -> bijective).

typedef int v4i __attribute__((ext_vector_type(4)));

__device__ __forceinline__ void async_copy16(const void* g, void* s) {
  __builtin_amdgcn_global_load_lds(
      (const __attribute__((address_space(1))) void*)g,
      (__attribute__((address_space(3))) void*)s, 16, 0, 0);
}

__device__ __forceinline__ float block_max(float m) {
  __shared__ float smax[4];
#pragma unroll
  for (int off = 32; off > 0; off >>= 1)
    m = fmaxf(m, __shfl_down(m, off, 64));
  if ((threadIdx.x & 63) == 0) smax[threadIdx.x >> 6] = m;
  __syncthreads();
  return fmaxf(fmaxf(smax[0], smax[1]), fmaxf(smax[2], smax[3]));
}

#define NBX 1024
#define NBW 512

__global__ __launch_bounds__(256) void absmax_partial_kernel(
    const float4* __restrict__ x, int xn4, const float4* __restrict__ w,
    int wn4, float* __restrict__ px, float* __restrict__ pw) {
  const float4* src;
  float* dst;
  int n4, bid, nb;
  if (blockIdx.x < NBX) {
    src = x; n4 = xn4; dst = px; bid = blockIdx.x; nb = NBX;
  } else {
    src = w; n4 = wn4; dst = pw; bid = blockIdx.x - NBX; nb = NBW;
  }
  float m = 0.0f;
  for (int i = bid * 256 + threadIdx.x; i < n4; i += nb * 256) {
    float4 v = src[i];
    m = fmaxf(m, fmaxf(fmaxf(fabsf(v.x), fabsf(v.y)),
                       fmaxf(fabsf(v.z), fabsf(v.w))));
  }
  m = block_max(m);
  if (threadIdx.x == 0) dst[bid] = m;
}

__global__ __launch_bounds__(256) void absmax_final_kernel(
    const float* __restrict__ px, const float* __restrict__ pw,
    float* __restrict__ sat) {
  const float* src = (blockIdx.x == 0) ? px : pw;
  const int n = (blockIdx.x == 0) ? NBX : NBW;
  float m = 0.0f;
  for (int i = threadIdx.x; i < n; i += 256) m = fmaxf(m, src[i]);
  m = block_max(m);
  if (threadIdx.x == 0) {
    sat[blockIdx.x] = m;
    sat[2 + blockIdx.x] = 127.0f / fmaxf(m, 1e-8f);
  }
}

__device__ __forceinline__ int pack4(float4 v, float inv) {
  int a = (int)fminf(fmaxf(rintf(v.x * inv), -128.0f), 127.0f);
  int b = (int)fminf(fmaxf(rintf(v.y * inv), -128.0f), 127.0f);
  int c = (int)fminf(fmaxf(rintf(v.z * inv), -128.0f), 127.0f);
  int d = (int)fminf(fmaxf(rintf(v.w * inv), -128.0f), 127.0f);
  return (a & 255) | ((b & 255) << 8) | ((c & 255) << 16) | ((d & 255) << 24);
}

#define QNB 2048

__global__ __launch_bounds__(256) void quant_fused_kernel(
    const float4* __restrict__ x, int xn16, const float4* __restrict__ w,
    int wn16, const float* __restrict__ sat, int4* __restrict__ xq,
    int4* __restrict__ wq) {
  const float invx = sat[2];
  const float invw = sat[3];
  const int nth = QNB * 256;
  const int t = blockIdx.x * 256 + threadIdx.x;
  for (int u = t; u < xn16; u += nth) {
    const float4* p = x + (size_t)u * 4;
    int4 o;
    o.x = pack4(p[0], invx);
    o.y = pack4(p[1], invx);
    o.z = pack4(p[2], invx);
    o.w = pack4(p[3], invx);
    xq[u] = o;
  }
  for (int u = t; u < wn16; u += nth) {
    const float4* p = w + (size_t)u * 4;
    int4 o;
    o.x = pack4(p[0], invw);
    o.y = pack4(p[1], invw);
    o.z = pack4(p[2], invw);
    o.w = pack4(p[3], invw);
    wq[u] = o;
  }
}

// C[m,n] = sum_k A[m,k]*B[n,k]; A = x_int8 [M,K], B = w_int8 [N,K].
// 256x256 tile, 512 threads (8 waves: 2 M-rows x 4 N-cols), BK = 64 bytes,
// 4-deep circular K-tile LDS pipeline.
__global__ __launch_bounds__(512, 2) void i8_gemm_kernel(
    const signed char* __restrict__ Aq, const signed char* __restrict__ Bq,
    const float* __restrict__ bias, const float* __restrict__ sat,
    float* __restrict__ out, int M, int N, int K) {
  __shared__ signed char lds[4][2][256 * 64];  // [buf][A/B][row*64 + chunk*16]

  const int tid = threadIdx.x;
  const int lane = tid & 63;
  const int wid = tid >> 6;  // 0..7
  const int wr = wid >> 2;   // 0..1  (M half)
  const int wc = wid & 3;    // 0..3  (N quarter)
  const int r15 = lane & 15;
  const int q4 = lane >> 4;

  const int nwg = gridDim.x * gridDim.y;
  int bid = blockIdx.y * gridDim.x + blockIdx.x;
  if ((nwg & 7) == 0) bid = (bid & 7) * (nwg >> 3) + (bid >> 3);
  const int N0 = (bid % gridDim.x) * 256;
  const int M0 = (bid / gridDim.x) * 256;

  // ---- staging (write side): LDS dest is linear tid*16 (forced by
  // global_load_lds); slot sb of row srow holds global chunk cg with
  // sb = (cg + ((row>>1)&3)) & 3  ->  cg = (sb - ((srow>>1)&3)) & 3.
  // Rows srow and srow+128 share ((row>>1)&3) since 128&3==0... (128>>1)&3==0:
  // (srow+128)>>1 = srow>>1 + 64; 64&3==0 -> same swizzle bits. OK.
  const int srow = tid >> 2;  // 0..127
  const int sb = tid & 3;     // chunk slot 0..3
  const int cg = (sb - ((srow >> 1) & 3)) & 3;
  const signed char* Ag = Aq + (size_t)(M0 + srow) * K + cg * 16;
  const signed char* Bg = Bq + (size_t)(N0 + srow) * K + cg * 16;
  const int d0 = srow * 64 + sb * 16;  // == tid*16
  const size_t rstep = (size_t)128 * K;

  // ---- read side: chunk q4 of row (.. + r15) sits at slot (q4+((r15>>1)&3))&3.
  const int kboff = ((q4 + ((r15 >> 1) & 3)) & 3) * 16;

  v4i acc[8][4] = {};
  const int nt = K >> 6;

  // Prologue: stage tiles 0,1,2 (4 loads/thread each).
  for (int T = 0; T < 3; ++T) {
    const size_t ko = (size_t)T << 6;
    signed char* bA = &lds[T & 3][0][0];
    signed char* bB = &lds[T & 3][1][0];
    async_copy16(Ag + ko, bA + d0);
    async_copy16(Ag + ko + rstep, bA + d0 + 8192);
    async_copy16(Bg + ko, bB + d0);
    async_copy16(Bg + ko + rstep, bB + d0 + 8192);
  }
  asm volatile("s_waitcnt vmcnt(8)" ::: "memory");  // tile 0 landed
  __builtin_amdgcn_s_barrier();

  for (int t = 0; t < nt; ++t) {
    const signed char* bA = &lds[t & 3][0][0];
    const signed char* bB = &lds[t & 3][1][0];
    const int tp = t + 3;
    const bool st = tp < nt;
    signed char* sA = &lds[tp & 3][0][0];
    signed char* sB = &lds[tp & 3][1][0];
    const size_t ko = (size_t)tp << 6;

    v4i af[4], bf[4];

    // ================= phase A (m-half 0) =================
#pragma unroll
    for (int f = 0; f < 4; ++f) {
      af[f] = *(const v4i*)(bA + (wr * 128 + f * 16 + r15) * 64 + kboff);
      bf[f] = *(const v4i*)(bB + (wc * 64 + f * 16 + r15) * 64 + kboff);
    }
    if (st) {  // stage A-halves of tile t+3 (slot freed by barrier @ t-1)
      async_copy16(Ag + ko, sA + d0);
      async_copy16(Ag + ko + rstep, sA + d0 + 8192);
    }
    __builtin_amdgcn_s_barrier();
    asm volatile("s_waitcnt lgkmcnt(0)" ::: "memory");
    __builtin_amdgcn_sched_barrier(0);
    __builtin_amdgcn_s_setprio(1);
#pragma unroll
    for (int fm = 0; fm < 4; ++fm)
#pragma unroll
      for (int fn = 0; fn < 4; ++fn)
        acc[fm][fn] = __builtin_amdgcn_mfma_i32_16x16x64_i8(
            af[fm], bf[fn], acc[fm][fn], 0, 0, 0);
    __builtin_amdgcn_s_setprio(0);
    __builtin_amdgcn_s_barrier();

    // ================= phase B (m-half 1, B-frags reused) =================
#pragma unroll
    for (int f = 0; f < 4; ++f) {
      af[f] = *(const v4i*)(bA + (wr * 128 + 64 + f * 16 + r15) * 64 + kboff);
    }
    if (st) {  // stage B-halves of tile t+3
      async_copy16(Bg + ko, sB + d0);
      async_copy16(Bg + ko + rstep, sB + d0 + 8192);
    }
    __builtin_amdgcn_s_barrier();
    asm volatile("s_waitcnt lgkmcnt(0)" ::: "memory");
    __builtin_amdgcn_sched_barrier(0);
    __builtin_amdgcn_s_setprio(1);
#pragma unroll
    for (int fm = 0; fm < 4; ++fm)
#pragma unroll
      for (int fn = 0; fn < 4; ++fn)
        acc[4 + fm][fn] = __builtin_amdgcn_mfma_i32_16x16x64_i8(
            af[fm], bf[fn], acc[4 + fm][fn], 0, 0, 0);
    __builtin_amdgcn_s_setprio(0);
    // Counted vmcnt once per K-tile: ensure tile t+1 fully landed, keep
    // tiles t+2,t+3 (8 loads) in flight. Tail drains 8 -> 4 -> 0.
    if (t < nt - 3) {
      asm volatile("s_waitcnt vmcnt(8)" ::: "memory");
    } else if (t == nt - 3) {
      asm volatile("s_waitcnt vmcnt(4)" ::: "memory");
    } else if (t == nt - 2) {
      asm volatile("s_waitcnt vmcnt(0)" ::: "memory");
    }
    __builtin_amdgcn_s_barrier();
  }

  const float act_s = fmaxf(sat[0], 1e-8f) / 127.0f;
  const float w_s = fmaxf(sat[1], 1e-8f) / 127.0f;
  const float bscale = act_s * w_s;

  // C/D layout (16x16 shapes): col = lane&15, row = (lane>>4)*4 + reg
#pragma unroll
  for (int fn = 0; fn < 4; ++fn) {
    const int col = N0 + wc * 64 + fn * 16 + r15;
    const float fb = rintf(bias[col] / bscale);
#pragma unroll
    for (int f = 0; f < 8; ++f) {
      const int row0 = M0 + wr * 128 + f * 16 + q4 * 4;
#pragma unroll
      for (int rr = 0; rr < 4; ++rr) {
        out[(size_t)(row0 + rr) * N + col] =
            ((float)acc[f][fn][rr] + fb) * bscale;
      }
    }
  }
}

extern "C" void kernel_launch(void* const* d_in, const int* in_sizes, int n_in,
                              void* d_out, int out_size, void* d_ws,
                              size_t ws_size, hipStream_t stream) {
  const float* x = (const float*)d_in[0];
  const float* W = (const float*)d_in[1];
  const float* b = (const float*)d_in[2];
  float* out = (float*)d_out;

  const int Dout = in_sizes[2];      // 4096
  const int K = in_sizes[1] / Dout;  // 4096
  const int M = in_sizes[0] / K;     // 8192
  const int N = Dout;

  float* sat = (float*)d_ws;
  float* px = sat + 16;
  float* pw = px + NBX;
  signed char* xq = (signed char*)d_ws + 8192;
  signed char* wq = xq + (size_t)M * K;

  const int xn4 = in_sizes[0] / 4;
  const int wn4 = in_sizes[1] / 4;

  absmax_partial_kernel<<<NBX + NBW, 256, 0, stream>>>(
      (const float4*)x, xn4, (const float4*)W, wn4, px, pw);
  absmax_final_kernel<<<2, 256, 0, stream>>>(px, pw, sat);
  quant_fused_kernel<<<QNB, 256, 0, stream>>>(
      (const float4*)x, xn4 / 4, (const float4*)W, wn4 / 4, sat, (int4*)xq,
      (int4*)wq);

  dim3 grid(N / 256, M / 256);
  i8_gemm_kernel<<<grid, 512, 0, stream>>>(xq, wq, b, sat, out, M, N, K);
}

// Round 6
// 413.091 us; speedup vs baseline: 1.1937x; 1.0609x over previous
//
#include <hip/hip_runtime.h>
#include <cstdint>
#include <cstddef>

// R6b: identical to R6 except the nontemporal store uses a clang
// ext_vector_type float4 (v4f) — __builtin_nontemporal_store rejects HIP's
// float4 class type. No perf-relevant changes vs R6.
//  1) absmax partials (no atomics) -> quant kernel self-reduces the partials
//     (absmax_final dispatch DELETED; quant publishes sat[0..1]).
//  2) fused quantize x->int8 [M,K], W->int8 [N,K] (64B/thread, mul-by-recip).
//  3) int8 MFMA GEMM, R5 sync structure (verified 158us, MfmaUtil 37%,
//     0 bank conflicts) + x4-unrolled K-loop (compile-time buffer indices)
//     + coalesced LDS-scratch epilogue (full 256B row segments, v4f
//     nontemporal stores, float4 bias load).

typedef int v4i __attribute__((ext_vector_type(4)));
typedef float v4f __attribute__((ext_vector_type(4)));

__device__ __forceinline__ void async_copy16(const void* g, void* s) {
  __builtin_amdgcn_global_load_lds(
      (const __attribute__((address_space(1))) void*)g,
      (__attribute__((address_space(3))) void*)s, 16, 0, 0);
}

__device__ __forceinline__ float block_max(float m) {
  __shared__ float smax[4];
#pragma unroll
  for (int off = 32; off > 0; off >>= 1)
    m = fmaxf(m, __shfl_down(m, off, 64));
  if ((threadIdx.x & 63) == 0) smax[threadIdx.x >> 6] = m;
  __syncthreads();
  return fmaxf(fmaxf(smax[0], smax[1]), fmaxf(smax[2], smax[3]));
}

#define NBX 1024
#define NBW 512

__global__ __launch_bounds__(256) void absmax_partial_kernel(
    const float4* __restrict__ x, int xn4, const float4* __restrict__ w,
    int wn4, float* __restrict__ px, float* __restrict__ pw) {
  const float4* src;
  float* dst;
  int n4, bid, nb;
  if (blockIdx.x < NBX) {
    src = x; n4 = xn4; dst = px; bid = blockIdx.x; nb = NBX;
  } else {
    src = w; n4 = wn4; dst = pw; bid = blockIdx.x - NBX; nb = NBW;
  }
  float m = 0.0f;
  for (int i = bid * 256 + threadIdx.x; i < n4; i += nb * 256) {
    float4 v = src[i];
    m = fmaxf(m, fmaxf(fmaxf(fabsf(v.x), fabsf(v.y)),
                       fmaxf(fabsf(v.z), fabsf(v.w))));
  }
  m = block_max(m);
  if (threadIdx.x == 0) dst[bid] = m;
}

__device__ __forceinline__ int pack4(float4 v, float inv) {
  int a = (int)fminf(fmaxf(rintf(v.x * inv), -128.0f), 127.0f);
  int b = (int)fminf(fmaxf(rintf(v.y * inv), -128.0f), 127.0f);
  int c = (int)fminf(fmaxf(rintf(v.z * inv), -128.0f), 127.0f);
  int d = (int)fminf(fmaxf(rintf(v.w * inv), -128.0f), 127.0f);
  return (a & 255) | ((b & 255) << 8) | ((c & 255) << 16) | ((d & 255) << 24);
}

#define QNB 2048

__global__ __launch_bounds__(256) void quant_fused_kernel(
    const float4* __restrict__ x, int xn16, const float4* __restrict__ w,
    int wn16, const float* __restrict__ px, const float* __restrict__ pw,
    float* __restrict__ sat, int4* __restrict__ xq, int4* __restrict__ wq) {
  // Self-reduce the absmax partials (replaces the absmax_final dispatch).
  float mx = 0.0f, mw = 0.0f;
  for (int i = threadIdx.x; i < NBX; i += 256) mx = fmaxf(mx, px[i]);
  mx = block_max(mx);
  __syncthreads();  // protect smax reuse between the two block_max calls
  for (int i = threadIdx.x; i < NBW; i += 256) mw = fmaxf(mw, pw[i]);
  mw = block_max(mw);
  if (blockIdx.x == 0 && threadIdx.x == 0) {
    sat[0] = mx;  // for the GEMM epilogue
    sat[1] = mw;
  }
  const float invx = 127.0f / fmaxf(mx, 1e-8f);
  const float invw = 127.0f / fmaxf(mw, 1e-8f);

  const int nth = QNB * 256;
  const int t = blockIdx.x * 256 + threadIdx.x;
  for (int u = t; u < xn16; u += nth) {
    const float4* p = x + (size_t)u * 4;
    int4 o;
    o.x = pack4(p[0], invx);
    o.y = pack4(p[1], invx);
    o.z = pack4(p[2], invx);
    o.w = pack4(p[3], invx);
    xq[u] = o;
  }
  for (int u = t; u < wn16; u += nth) {
    const float4* p = w + (size_t)u * 4;
    int4 o;
    o.x = pack4(p[0], invw);
    o.y = pack4(p[1], invw);
    o.z = pack4(p[2], invw);
    o.w = pack4(p[3], invw);
    wq[u] = o;
  }
}

// One K-tile (BK=64 bytes) of the GEMM pipeline. CB/SB are the compute /
// stage LDS buffer indices (compile-time literals in the unrolled main loop,
// runtime in the tail). Sync structure IDENTICAL to R5.
#define GEMM_KTILE(CB, SB, T, ST, VMSEL)                                       \
  do {                                                                         \
    const signed char* bA_ = &lds[CB][0][0];                                   \
    const signed char* bB_ = &lds[CB][1][0];                                   \
    signed char* sA_ = &lds[SB][0][0];                                         \
    signed char* sB_ = &lds[SB][1][0];                                         \
    const size_t ko_ = (size_t)((T) + 3) << 6;                                 \
    v4i af_[4], bf_[4];                                                        \
    _Pragma("unroll") for (int f = 0; f < 4; ++f) {                            \
      af_[f] = *(const v4i*)(bA_ + (wr * 128 + f * 16 + r15) * 64 + kboff);    \
      bf_[f] = *(const v4i*)(bB_ + (wc * 64 + f * 16 + r15) * 64 + kboff);     \
    }                                                                          \
    if (ST) {                                                                  \
      async_copy16(Ag + ko_, sA_ + d0);                                        \
      async_copy16(Ag + ko_ + rstep, sA_ + d0 + 8192);                         \
    }                                                                          \
    __builtin_amdgcn_s_barrier();                                              \
    asm volatile("s_waitcnt lgkmcnt(0)" ::: "memory");                         \
    __builtin_amdgcn_sched_barrier(0);                                         \
    __builtin_amdgcn_s_setprio(1);                                             \
    _Pragma("unroll") for (int fm = 0; fm < 4; ++fm)                           \
        _Pragma("unroll") for (int fn = 0; fn < 4; ++fn) acc[fm][fn] =         \
        __builtin_amdgcn_mfma_i32_16x16x64_i8(af_[fm], bf_[fn], acc[fm][fn],   \
                                              0, 0, 0);                        \
    __builtin_amdgcn_s_setprio(0);                                             \
    __builtin_amdgcn_s_barrier();                                              \
    _Pragma("unroll") for (int f = 0; f < 4; ++f) {                            \
      af_[f] =                                                                 \
          *(const v4i*)(bA_ + (wr * 128 + 64 + f * 16 + r15) * 64 + kboff);    \
    }                                                                          \
    if (ST) {                                                                  \
      async_copy16(Bg + ko_, sB_ + d0);                                        \
      async_copy16(Bg + ko_ + rstep, sB_ + d0 + 8192);                         \
    }                                                                          \
    __builtin_amdgcn_s_barrier();                                              \
    asm volatile("s_waitcnt lgkmcnt(0)" ::: "memory");                         \
    __builtin_amdgcn_sched_barrier(0);                                         \
    __builtin_amdgcn_s_setprio(1);                                             \
    _Pragma("unroll") for (int fm = 0; fm < 4; ++fm)                           \
        _Pragma("unroll") for (int fn = 0; fn < 4; ++fn) acc[4 + fm][fn] =     \
        __builtin_amdgcn_mfma_i32_16x16x64_i8(af_[fm], bf_[fn],                \
                                              acc[4 + fm][fn], 0, 0, 0);       \
    __builtin_amdgcn_s_setprio(0);                                             \
    if ((VMSEL) == 0) {                                                        \
      asm volatile("s_waitcnt vmcnt(8)" ::: "memory");                         \
    } else if ((VMSEL) == 1) {                                                 \
      asm volatile("s_waitcnt vmcnt(4)" ::: "memory");                         \
    } else if ((VMSEL) == 2) {                                                 \
      asm volatile("s_waitcnt vmcnt(0)" ::: "memory");                         \
    }                                                                          \
    __builtin_amdgcn_s_barrier();                                              \
  } while (0)

// C[m,n] = sum_k A[m,k]*B[n,k]; A = x_int8 [M,K], B = w_int8 [N,K].
// 256x256 tile, 512 threads (8 waves: 2Mx4N), BK=64B, 4-deep circular LDS
// K-tile pipeline, counted vmcnt(8), unrolled x4 main loop.
__global__ __launch_bounds__(512, 2) void i8_gemm_kernel(
    const signed char* __restrict__ Aq, const signed char* __restrict__ Bq,
    const float* __restrict__ bias, const float* __restrict__ sat,
    float* __restrict__ out, int M, int N, int K) {
  __shared__ signed char lds[4][2][256 * 64];  // [buf][A/B][row*64 + chunk*16]

  const int tid = threadIdx.x;
  const int lane = tid & 63;
  const int wid = tid >> 6;  // 0..7
  const int wr = wid >> 2;   // 0..1  (M half)
  const int wc = wid & 3;    // 0..3  (N quarter)
  const int r15 = lane & 15;
  const int q4 = lane >> 4;

  const int nwg = gridDim.x * gridDim.y;
  int bid = blockIdx.y * gridDim.x + blockIdx.x;
  if ((nwg & 7) == 0) bid = (bid & 7) * (nwg >> 3) + (bid >> 3);
  const int N0 = (bid % gridDim.x) * 256;
  const int M0 = (bid / gridDim.x) * 256;

  // Staging (write side): linear LDS dest tid*16 (forced by global_load_lds);
  // slot sb of row srow holds global chunk cg = (sb - ((srow>>1)&3)) & 3.
  const int srow = tid >> 2;  // 0..127
  const int sb = tid & 3;     // chunk slot 0..3
  const int cg = (sb - ((srow >> 1) & 3)) & 3;
  const signed char* Ag = Aq + (size_t)(M0 + srow) * K + cg * 16;
  const signed char* Bg = Bq + (size_t)(N0 + srow) * K + cg * 16;
  const int d0 = srow * 64 + sb * 16;  // == tid*16
  const size_t rstep = (size_t)128 * K;

  // Read side: chunk q4 of row (..+r15) sits at slot (q4+((r15>>1)&3))&3.
  const int kboff = ((q4 + ((r15 >> 1) & 3)) & 3) * 16;

  v4i acc[8][4] = {};
  const int nt = K >> 6;

  // Prologue: stage tiles 0,1,2 (4 loads/thread each).
  for (int T = 0; T < 3; ++T) {
    const size_t ko = (size_t)T << 6;
    signed char* bA = &lds[T & 3][0][0];
    signed char* bB = &lds[T & 3][1][0];
    async_copy16(Ag + ko, bA + d0);
    async_copy16(Ag + ko + rstep, bA + d0 + 8192);
    async_copy16(Bg + ko, bB + d0);
    async_copy16(Bg + ko + rstep, bB + d0 + 8192);
  }
  asm volatile("s_waitcnt vmcnt(8)" ::: "memory");  // tile 0 landed
  __builtin_amdgcn_s_barrier();

  // Main loop unrolled x4: buffer indices are compile-time (t0 % 4 == 0).
  int t = 0;
  for (; t + 7 < nt; t += 4) {
    GEMM_KTILE(0, 3, t + 0, true, 0);
    GEMM_KTILE(1, 0, t + 1, true, 0);
    GEMM_KTILE(2, 1, t + 2, true, 0);
    GEMM_KTILE(3, 2, t + 3, true, 0);
  }
  // Tail (<= 7 tiles): runtime buffer select + vmcnt drain 8 -> 4 -> 0.
  for (; t < nt; ++t) {
    const int cb = t & 3;
    const int sbuf = (t + 3) & 3;
    const bool st = (t + 3) < nt;
    const int vmsel =
        (t < nt - 3) ? 0 : (t == nt - 3) ? 1 : (t == nt - 2) ? 2 : 3;
    GEMM_KTILE(cb, sbuf, t, st, vmsel);
  }

  const float act_s = fmaxf(sat[0], 1e-8f) / 127.0f;
  const float w_s = fmaxf(sat[1], 1e-8f) / 127.0f;
  const float bscale = act_s * w_s;

  // Coalesced epilogue. Per-wave-private 16KB LDS scratch (all staging DMA
  // retired: vmcnt drained to 0; all LDS reads retired: final barrier).
  // MFMA C/D layout: col = lane&15 (=r15), row = q4*4 + reg. Scatter acc into
  // scratch[64][64] f32, then read back 16B/lane row-contiguous and store
  // full 256B row segments. lgkmcnt is wave-scoped -> no barrier needed.
  float* scratch = (float*)&lds[0][0][0] + wid * 4096;
  const float4 b4 = *(const float4*)&bias[N0 + wc * 64 + 4 * r15];
  v4f fb4;
  fb4.x = rintf(b4.x / bscale);
  fb4.y = rintf(b4.y / bscale);
  fb4.z = rintf(b4.z / bscale);
  fb4.w = rintf(b4.w / bscale);

#pragma unroll
  for (int g = 0; g < 2; ++g) {
#pragma unroll
    for (int f4 = 0; f4 < 4; ++f4)
#pragma unroll
      for (int fn = 0; fn < 4; ++fn)
#pragma unroll
        for (int rr = 0; rr < 4; ++rr)
          scratch[(f4 * 16 + q4 * 4 + rr) * 64 + fn * 16 + r15] =
              (float)acc[g * 4 + f4][fn][rr];
    // compiler emits lgkmcnt wait for the may-alias RAW on scratch
#pragma unroll
    for (int rq = 0; rq < 16; ++rq) {
      v4f v = *(v4f*)&scratch[(rq * 4 + q4) * 64 + 4 * r15];
      v4f o = (v + fb4) * bscale;
      const int row = M0 + wr * 128 + g * 64 + rq * 4 + q4;
      __builtin_nontemporal_store(
          o, (v4f*)&out[(size_t)row * N + N0 + wc * 64 + 4 * r15]);
    }
  }
}

extern "C" void kernel_launch(void* const* d_in, const int* in_sizes, int n_in,
                              void* d_out, int out_size, void* d_ws,
                              size_t ws_size, hipStream_t stream) {
  const float* x = (const float*)d_in[0];
  const float* W = (const float*)d_in[1];
  const float* b = (const float*)d_in[2];
  float* out = (float*)d_out;

  const int Dout = in_sizes[2];      // 4096
  const int K = in_sizes[1] / Dout;  // 4096
  const int M = in_sizes[0] / K;     // 8192
  const int N = Dout;

  float* sat = (float*)d_ws;
  float* px = sat + 16;
  float* pw = px + NBX;
  signed char* xq = (signed char*)d_ws + 8192;
  signed char* wq = xq + (size_t)M * K;

  const int xn4 = in_sizes[0] / 4;
  const int wn4 = in_sizes[1] / 4;

  absmax_partial_kernel<<<NBX + NBW, 256, 0, stream>>>(
      (const float4*)x, xn4, (const float4*)W, wn4, px, pw);
  quant_fused_kernel<<<QNB, 256, 0, stream>>>(
      (const float4*)x, xn4 / 4, (const float4*)W, wn4 / 4, px, pw, sat,
      (int4*)xq, (int4*)wq);

  dim3 grid(N / 256, M / 256);
  i8_gemm_kernel<<<grid, 512, 0, stream>>>(xq, wq, b, sat, out, M, N, K);
}